// Round 2
// baseline (612.935 us; speedup 1.0000x reference)
//
#include <hip/hip_runtime.h>
#include <math.h>

typedef unsigned short u16;

__device__ __forceinline__ float bf2f(u16 u) {
    return __uint_as_float(((unsigned)u) << 16);
}
__device__ __forceinline__ u16 f2bf(float f) {
    unsigned u = __float_as_uint(f);
    unsigned r = (u + 0x7fffu + ((u >> 16) & 1u)) >> 16;  // RNE
    return (u16)r;
}

// ---------------- graph build ----------------

__global__ __launch_bounds__(256) void k_count(const int* __restrict__ ei, int E, int* __restrict__ cnt) {
    int e = blockIdx.x * 256 + threadIdx.x;
    if (e < E) atomicAdd(&cnt[ei[E + e]], 1);
}

__global__ __launch_bounds__(256) void k_dinv_alloc(const int* __restrict__ cnt, int N,
                                                    float* __restrict__ dinv, int* __restrict__ row_start,
                                                    int* __restrict__ cursor) {
    int v = blockIdx.x * 256 + threadIdx.x;
    if (v < N) {
        int c = cnt[v];
        dinv[v] = rsqrtf((float)(c + 1));  // deg includes self-loop
        row_start[v] = atomicAdd(cursor, c);
    }
}

__global__ __launch_bounds__(256) void k_fill(const int* __restrict__ ei, int E,
                                              const float* __restrict__ dinv,
                                              const int* __restrict__ row_start, int* __restrict__ fill,
                                              int2* __restrict__ edges) {
    int e = blockIdx.x * 256 + threadIdx.x;
    if (e < E) {
        int s = ei[e];
        int d = ei[E + e];
        float w = dinv[s] * dinv[d];
        int pos = row_start[d] + atomicAdd(&fill[d], 1);
        edges[pos] = make_int2(s, __float_as_int(w));
    }
}

// ---------------- dense GEMM: Y[N,M] = X[N,K] @ W[K,M], fp32, W staged bf16 in LDS ----------------

template <int K, int M>
__global__ __launch_bounds__(256) void k_gemm(const float* __restrict__ X, const float* __restrict__ Wg,
                                              float* __restrict__ Y, int N) {
    constexpr int ROWS = 4096 / M;  // 32 (M=128) or 64 (M=64)
    constexpr int XS = ROWS + 8;    // padded stride (multiple of 4 floats)
    __shared__ __align__(16) u16 Ws[K * M];
    __shared__ __align__(16) float Xs[K * XS];
    const int t = threadIdx.x;
    const int row0 = blockIdx.x * ROWS;

    for (int i = t * 4; i < K * M; i += 1024) {
        float4 w = *(const float4*)&Wg[i];
        Ws[i] = f2bf(w.x);
        Ws[i + 1] = f2bf(w.y);
        Ws[i + 2] = f2bf(w.z);
        Ws[i + 3] = f2bf(w.w);
    }
    for (int i = t; i < ROWS * K; i += 256) {
        int ri = i / K, kk = i - ri * K;
        int r = row0 + ri;
        Xs[kk * XS + ri] = (r < N) ? X[(size_t)r * K + kk] : 0.f;
    }
    __syncthreads();

    constexpr int CG = M / 4;
    const int cg = t % CG;
    const int rg = t / CG;
    float acc[4][4] = {};
    for (int k = 0; k < K; ++k) {
        const float4 xv = *(const float4*)&Xs[k * XS + rg * 4];
        float xr[4] = {xv.x, xv.y, xv.z, xv.w};
        const u16* wp = &Ws[k * M + cg * 4];
        float wf[4] = {bf2f(wp[0]), bf2f(wp[1]), bf2f(wp[2]), bf2f(wp[3])};
#pragma unroll
        for (int i = 0; i < 4; ++i)
#pragma unroll
            for (int j = 0; j < 4; ++j) acc[i][j] = fmaf(xr[i], wf[j], acc[i][j]);
    }
#pragma unroll
    for (int i = 0; i < 4; ++i) {
        int r = row0 + rg * 4 + i;
        if (r >= N) continue;
        *(float4*)&Y[(size_t)r * M + cg * 4] = make_float4(acc[i][0], acc[i][1], acc[i][2], acc[i][3]);
    }
}

// ---------------- CSR aggregation: out[v] = sum_e w_e * h[src_e] + dinv[v]^2 * h[v] + bias ----------------

template <int C, bool RELU>
__global__ __launch_bounds__(256) void k_agg(const float* __restrict__ hin, const int2* __restrict__ edges,
                                             const int* __restrict__ row_start, const int* __restrict__ cnt,
                                             const float* __restrict__ dinv, const float* __restrict__ bias,
                                             float* __restrict__ out, int N) {
    const int v = blockIdx.x * 4 + (threadIdx.x >> 6);
    const int lane = threadIdx.x & 63;
    if (v >= N) return;
    const int start = row_start[v];
    const int c = cnt[v];
    if (C == 128) {
        const float2* hp = (const float2*)hin;  // row = 64 float2
        float a0 = 0.f, a1 = 0.f;
        int i = 0;
        for (; i + 2 <= c; i += 2) {
            int2 p0 = edges[start + i];
            int2 p1 = edges[start + i + 1];
            float2 h0 = hp[(size_t)p0.x * 64 + lane];
            float2 h1 = hp[(size_t)p1.x * 64 + lane];
            float w0 = __int_as_float(p0.y), w1 = __int_as_float(p1.y);
            a0 = fmaf(w0, h0.x, a0);
            a1 = fmaf(w0, h0.y, a1);
            a0 = fmaf(w1, h1.x, a0);
            a1 = fmaf(w1, h1.y, a1);
        }
        if (i < c) {
            int2 p = edges[start + i];
            float2 h = hp[(size_t)p.x * 64 + lane];
            float w = __int_as_float(p.y);
            a0 = fmaf(w, h.x, a0);
            a1 = fmaf(w, h.y, a1);
        }
        float dv = dinv[v];
        float sw = dv * dv;
        float2 hs = hp[(size_t)v * 64 + lane];
        a0 = fmaf(sw, hs.x, a0);
        a1 = fmaf(sw, hs.y, a1);
        float2 bp = ((const float2*)bias)[lane];
        a0 += bp.x;
        a1 += bp.y;
        if (RELU) {
            a0 = fmaxf(a0, 0.f);
            a1 = fmaxf(a1, 0.f);
        }
        ((float2*)out)[(size_t)v * 64 + lane] = make_float2(a0, a1);
    } else {  // C == 64
        float a0 = 0.f;
        int i = 0;
        for (; i + 2 <= c; i += 2) {
            int2 p0 = edges[start + i];
            int2 p1 = edges[start + i + 1];
            a0 = fmaf(__int_as_float(p0.y), hin[(size_t)p0.x * 64 + lane], a0);
            a0 = fmaf(__int_as_float(p1.y), hin[(size_t)p1.x * 64 + lane], a0);
        }
        if (i < c) {
            int2 p = edges[start + i];
            a0 = fmaf(__int_as_float(p.y), hin[(size_t)p.x * 64 + lane], a0);
        }
        float dv = dinv[v];
        a0 = fmaf(dv * dv, hin[(size_t)v * 64 + lane], a0);
        a0 += bias[lane];
        if (RELU) a0 = fmaxf(a0, 0.f);
        out[(size_t)v * 64 + lane] = a0;
    }
}

// ---------------- fused mu / logvar / z (z may alias H; per-block rows are LDS-staged first) ----------------

__global__ __launch_bounds__(256) void k_mulvz(const float* __restrict__ H, const float* __restrict__ Wmu,
                                               const float* __restrict__ bmu, const float* __restrict__ Wlv,
                                               const float* __restrict__ blv, const float* __restrict__ eps,
                                               float* __restrict__ omu, float* __restrict__ olv,
                                               float* z, int N) {
    __shared__ __align__(16) float Wm[64 * 64];
    __shared__ __align__(16) float Wl[64 * 64];
    __shared__ __align__(16) float Xs[64 * 72];
    const int t = threadIdx.x;
    const int row0 = blockIdx.x * 64;
    for (int i = t * 4; i < 64 * 64; i += 1024) {
        *(float4*)&Wm[i] = *(const float4*)&Wmu[i];
        *(float4*)&Wl[i] = *(const float4*)&Wlv[i];
    }
    for (int i = t; i < 64 * 64; i += 256) {
        int ri = i >> 6, kk = i & 63;
        int r = row0 + ri;
        Xs[kk * 72 + ri] = (r < N) ? H[(size_t)r * 64 + kk] : 0.f;
    }
    __syncthreads();
    const int cg = t & 15;
    const int rg = t >> 4;
    float am[4][4] = {}, al[4][4] = {};
    for (int k = 0; k < 64; ++k) {
        const float4 xv = *(const float4*)&Xs[k * 72 + rg * 4];
        const float4 wm4 = *(const float4*)&Wm[k * 64 + cg * 4];
        const float4 wl4 = *(const float4*)&Wl[k * 64 + cg * 4];
        float xr[4] = {xv.x, xv.y, xv.z, xv.w};
        float wmr[4] = {wm4.x, wm4.y, wm4.z, wm4.w};
        float wlr[4] = {wl4.x, wl4.y, wl4.z, wl4.w};
#pragma unroll
        for (int i = 0; i < 4; ++i)
#pragma unroll
            for (int j = 0; j < 4; ++j) {
                am[i][j] = fmaf(xr[i], wmr[j], am[i][j]);
                al[i][j] = fmaf(xr[i], wlr[j], al[i][j]);
            }
    }
#pragma unroll
    for (int i = 0; i < 4; ++i) {
        int r = row0 + rg * 4 + i;
        if (r >= N) continue;
#pragma unroll
        for (int j = 0; j < 4; ++j) {
            int cc = cg * 4 + j;
            float mu = am[i][j] + bmu[cc];
            float lv = al[i][j] + blv[cc];
            omu[(size_t)r * 64 + cc] = mu;
            olv[(size_t)r * 64 + cc] = lv;
            z[(size_t)r * 64 + cc] = mu + eps[(size_t)r * 64 + cc] * expf(0.5f * lv);
        }
    }
}

// ---------------- launch ----------------

extern "C" void kernel_launch(void* const* d_in, const int* in_sizes, int n_in,
                              void* d_out, int out_size, void* d_ws, size_t ws_size,
                              hipStream_t stream) {
    const float* x = (const float*)d_in[0];
    const int* ei = (const int*)d_in[1];
    const float* eps = (const float*)d_in[2];
    const float* We1 = (const float*)d_in[3];
    const float* be1 = (const float*)d_in[4];
    const float* We2 = (const float*)d_in[5];
    const float* be2 = (const float*)d_in[6];
    const float* Wmu = (const float*)d_in[7];
    const float* bmu = (const float*)d_in[8];
    const float* Wlv = (const float*)d_in[9];
    const float* blv = (const float*)d_in[10];
    const float* Wd1 = (const float*)d_in[11];
    const float* bd1 = (const float*)d_in[12];
    const float* Wd2 = (const float*)d_in[13];
    const float* bd2 = (const float*)d_in[14];

    const int N = in_sizes[0] / 128;  // 50000
    const int E = in_sizes[1] / 2;    // 800000

    // workspace layout
    int* cnt = (int*)d_ws;
    int* fill = cnt + N;
    int* cursor = fill + N;  // + pad to 64 ints
    float* dinv = (float*)(cursor + 64);
    int* row_start = (int*)(dinv + N);
    int2* edges = (int2*)(row_start + N);            // E entries
    float* R2 = (float*)(edges + E);                 // N*128 fp32 ping buffer (16B-aligned)

    float* out_d = (float*)d_out;                    // N*128 (also used as ping buffer R1)
    float* out_mu = out_d + (size_t)N * 128;         // N*64
    float* out_lv = out_mu + (size_t)N * 64;         // N*64
    float* R1 = out_d;

    hipMemsetAsync(d_ws, 0, (size_t)(2 * N + 64) * 4, stream);  // cnt, fill, cursor

    k_count<<<dim3((E + 255) / 256), dim3(256), 0, stream>>>(ei, E, cnt);
    k_dinv_alloc<<<dim3((N + 255) / 256), dim3(256), 0, stream>>>(cnt, N, dinv, row_start, cursor);
    k_fill<<<dim3((E + 255) / 256), dim3(256), 0, stream>>>(ei, E, dinv, row_start, fill, edges);

    // encoder conv1: relu(agg(x @ W_e1))
    k_gemm<128, 128><<<dim3((N + 31) / 32), dim3(256), 0, stream>>>(x, We1, R1, N);
    k_agg<128, true><<<dim3((N + 3) / 4), dim3(256), 0, stream>>>(R1, edges, row_start, cnt, dinv, be1, R2, N);
    // encoder conv2: agg(h @ W_e2)
    k_gemm<128, 64><<<dim3((N + 63) / 64), dim3(256), 0, stream>>>(R2, We2, R1, N);
    k_agg<64, false><<<dim3((N + 3) / 4), dim3(256), 0, stream>>>(R1, edges, row_start, cnt, dinv, be2, R2, N);
    // mu / logvar / z (z overwrites H in place; per-block safe)
    k_mulvz<<<dim3((N + 63) / 64), dim3(256), 0, stream>>>(R2, Wmu, bmu, Wlv, blv, eps, out_mu, out_lv, R2, N);
    // decoder conv1: relu(agg(z @ W_d1))
    k_gemm<64, 128><<<dim3((N + 31) / 32), dim3(256), 0, stream>>>(R2, Wd1, R1, N);
    k_agg<128, true><<<dim3((N + 3) / 4), dim3(256), 0, stream>>>(R1, edges, row_start, cnt, dinv, bd1, R2, N);
    // decoder conv2: agg(d1 @ W_d2) -> out_d    (gemm in-place on R2 is per-block safe)
    k_gemm<128, 128><<<dim3((N + 31) / 32), dim3(256), 0, stream>>>(R2, Wd2, R2, N);
    k_agg<128, false><<<dim3((N + 3) / 4), dim3(256), 0, stream>>>(R2, edges, row_start, cnt, dinv, bd2, out_d, N);
}

// Round 3
// 445.908 us; speedup vs baseline: 1.3746x; 1.3746x over previous
//
#include <hip/hip_runtime.h>
#include <math.h>

typedef unsigned short u16;
typedef unsigned int u32;
typedef __attribute__((ext_vector_type(8))) short s16x8;
typedef __attribute__((ext_vector_type(4))) float f32x4;

__device__ __forceinline__ float bf2f(u16 u) { return __uint_as_float(((u32)u) << 16); }
__device__ __forceinline__ u16 f2bf(float f) {
    u32 u = __float_as_uint(f);
    return (u16)((u + 0x7fffu + ((u >> 16) & 1u)) >> 16);  // RNE
}

union U4 { u32 u[4]; s16x8 v; };

// pack 8 fp32 -> 8 bf16 (truncation) ; lo = residual truncated
__device__ __forceinline__ s16x8 pack_hi(f32x4 x0, f32x4 x1) {
    U4 r;
    r.u[0] = (__float_as_uint(x0.y) & 0xFFFF0000u) | (__float_as_uint(x0.x) >> 16);
    r.u[1] = (__float_as_uint(x0.w) & 0xFFFF0000u) | (__float_as_uint(x0.z) >> 16);
    r.u[2] = (__float_as_uint(x1.y) & 0xFFFF0000u) | (__float_as_uint(x1.x) >> 16);
    r.u[3] = (__float_as_uint(x1.w) & 0xFFFF0000u) | (__float_as_uint(x1.z) >> 16);
    return r.v;
}
__device__ __forceinline__ s16x8 pack_lo(f32x4 x0, f32x4 x1) {
    float e0 = x0.x - __uint_as_float(__float_as_uint(x0.x) & 0xFFFF0000u);
    float e1 = x0.y - __uint_as_float(__float_as_uint(x0.y) & 0xFFFF0000u);
    float e2 = x0.z - __uint_as_float(__float_as_uint(x0.z) & 0xFFFF0000u);
    float e3 = x0.w - __uint_as_float(__float_as_uint(x0.w) & 0xFFFF0000u);
    float e4 = x1.x - __uint_as_float(__float_as_uint(x1.x) & 0xFFFF0000u);
    float e5 = x1.y - __uint_as_float(__float_as_uint(x1.y) & 0xFFFF0000u);
    float e6 = x1.z - __uint_as_float(__float_as_uint(x1.z) & 0xFFFF0000u);
    float e7 = x1.w - __uint_as_float(__float_as_uint(x1.w) & 0xFFFF0000u);
    U4 r;
    r.u[0] = (__float_as_uint(e1) & 0xFFFF0000u) | (__float_as_uint(e0) >> 16);
    r.u[1] = (__float_as_uint(e3) & 0xFFFF0000u) | (__float_as_uint(e2) >> 16);
    r.u[2] = (__float_as_uint(e5) & 0xFFFF0000u) | (__float_as_uint(e4) >> 16);
    r.u[3] = (__float_as_uint(e7) & 0xFFFF0000u) | (__float_as_uint(e6) >> 16);
    return r.v;
}

// ---------------- graph build ----------------

__global__ __launch_bounds__(256) void k_count(const int* __restrict__ ei, int E, int* __restrict__ cnt) {
    int e = blockIdx.x * 256 + threadIdx.x;
    if (e < E) atomicAdd(&cnt[ei[E + e]], 1);
}

__global__ __launch_bounds__(256) void k_dinv_alloc(const int* __restrict__ cnt, int N,
                                                    float* __restrict__ dinv, int* __restrict__ row_start,
                                                    int* __restrict__ cursor) {
    int v = blockIdx.x * 256 + threadIdx.x;
    if (v < N) {
        int c = cnt[v];
        dinv[v] = rsqrtf((float)(c + 1));
        row_start[v] = atomicAdd(cursor, c);
    }
}

__global__ __launch_bounds__(256) void k_fill(const int* __restrict__ ei, int E,
                                              const float* __restrict__ dinv,
                                              const int* __restrict__ row_start, int* __restrict__ fill,
                                              int2* __restrict__ edges) {
    int e = blockIdx.x * 256 + threadIdx.x;
    if (e < E) {
        int s = ei[e];
        int d = ei[E + e];
        float w = dinv[s] * dinv[d];
        int pos = row_start[d] + atomicAdd(&fill[d], 1);
        edges[pos] = make_int2(s, __float_as_int(w));
    }
}

// ---------------- split-precision MFMA GEMM ----------------
// Y[N,M] = X[N,K] @ W[K,M], X fp32, W fp32 split into bf16 hi/lo (3-MFMA per pair).
// Block: 256 thr (4 waves), covers RT*64 rows x 64 cols. NSET=2 -> dual weights (mu/lv+z fused).

template <int K, int RT, int NSET, bool OUT_BF16>
__global__ __launch_bounds__(256, 2) void k_gemm(const float* __restrict__ X,
                                                 const float* __restrict__ W0, const float* __restrict__ W1,
                                                 const float* __restrict__ b0, const float* __restrict__ b1,
                                                 const float* __restrict__ eps,
                                                 void* __restrict__ Y0, float* __restrict__ Y1,
                                                 float* __restrict__ Z, int N, int M) {
    constexpr int CH = K / 32;       // k-chunks of 32
    constexpr int NF = CH * 4 * 2;   // frags per weight set (4 col-tiles, hi/lo)
    __shared__ u16 Bs[NSET * NF * 512];
    const int t = threadIdx.x;
    const int lane = t & 63, w = t >> 6;
    const int l15 = lane & 15, q = lane >> 4;
    const int col0 = blockIdx.x * 64;
    const int row0 = blockIdx.y * (RT * 64);

    // stage W into LDS in MFMA B-fragment order (bf16 hi/lo)
    for (int s = 0; s < NSET; ++s) {
        const float* Wg = s ? W1 : W0;
        for (int f = t; f < K * 16; f += 256) {
            int k = f >> 4, c4 = (f & 15) << 2;
            f32x4 wv = *(const f32x4*)&Wg[(size_t)k * M + col0 + c4];
            int chunk = k >> 5, j = k & 7, lq = (k >> 3) & 3;
            float vv[4] = {wv.x, wv.y, wv.z, wv.w};
#pragma unroll
            for (int ii = 0; ii < 4; ++ii) {
                int c = c4 + ii;
                int ct = c >> 4, ln = (c & 15) + (lq << 4);
                int base = (s * NF + (chunk * 4 + ct) * 2) * 512 + ln * 8 + j;
                u32 ub = __float_as_uint(vv[ii]);
                float lof = vv[ii] - __uint_as_float(ub & 0xFFFF0000u);
                Bs[base] = (u16)(ub >> 16);
                Bs[base + 512] = (u16)(__float_as_uint(lof) >> 16);
            }
        }
    }
    __syncthreads();

    // preload all B fragments to registers
    s16x8 Bfr[NSET * NF];
#pragma unroll
    for (int f = 0; f < NSET * NF; ++f) Bfr[f] = *(const s16x8*)&Bs[f * 512 + lane * 8];

    f32x4 acc[NSET][RT][4];
#pragma unroll
    for (int s = 0; s < NSET; ++s)
#pragma unroll
        for (int rt = 0; rt < RT; ++rt)
#pragma unroll
            for (int ct = 0; ct < 4; ++ct) acc[s][rt][ct] = 0.f;

#pragma unroll
    for (int ch = 0; ch < CH; ++ch) {
#pragma unroll
        for (int rt = 0; rt < RT; ++rt) {
            int r = row0 + (w * RT + rt) * 16 + l15;
            r = r < N ? r : N - 1;
            const float* xp = X + (size_t)r * K + (ch << 5) + (q << 3);
            f32x4 x0 = *(const f32x4*)xp;
            f32x4 x1 = *(const f32x4*)(xp + 4);
            s16x8 ah = pack_hi(x0, x1);
            s16x8 al = pack_lo(x0, x1);
#pragma unroll
            for (int s = 0; s < NSET; ++s)
#pragma unroll
                for (int ct = 0; ct < 4; ++ct) {
                    int fb = s * NF + (ch * 4 + ct) * 2;
                    acc[s][rt][ct] = __builtin_amdgcn_mfma_f32_16x16x32_bf16(ah, Bfr[fb], acc[s][rt][ct], 0, 0, 0);
                    acc[s][rt][ct] = __builtin_amdgcn_mfma_f32_16x16x32_bf16(ah, Bfr[fb + 1], acc[s][rt][ct], 0, 0, 0);
                    acc[s][rt][ct] = __builtin_amdgcn_mfma_f32_16x16x32_bf16(al, Bfr[fb], acc[s][rt][ct], 0, 0, 0);
                }
        }
    }

    // epilogue: C/D layout col = lane&15, row = (lane>>4)*4 + reg
#pragma unroll
    for (int rt = 0; rt < RT; ++rt)
#pragma unroll
        for (int ct = 0; ct < 4; ++ct)
#pragma unroll
            for (int reg = 0; reg < 4; ++reg) {
                int row = row0 + (w * RT + rt) * 16 + q * 4 + reg;
                if (row >= N) continue;
                int col = col0 + ct * 16 + l15;
                if (NSET == 1) {
                    float v = acc[0][rt][ct][reg];
                    if (OUT_BF16)
                        ((u16*)Y0)[(size_t)row * M + col] = f2bf(v);
                    else
                        ((float*)Y0)[(size_t)row * M + col] = v;
                } else {
                    float mu = acc[0][rt][ct][reg] + b0[col];
                    float lv = acc[1][rt][ct][reg] + b1[col];
                    size_t o = (size_t)row * 64 + col;
                    ((float*)Y0)[o] = mu;
                    Y1[o] = lv;
                    Z[o] = mu + eps[o] * expf(0.5f * lv);
                }
            }
}

// ---------------- CSR aggregation (bf16 in, fp32 out) ----------------

template <bool RELU>
__global__ __launch_bounds__(256) void k_agg128(const u16* __restrict__ hin, const int2* __restrict__ edges,
                                                const int* __restrict__ row_start, const int* __restrict__ cnt,
                                                const float* __restrict__ dinv, const float* __restrict__ bias,
                                                float* __restrict__ out, int N) {
    const int v = blockIdx.x * 4 + (threadIdx.x >> 6);
    const int lane = threadIdx.x & 63;
    if (v >= N) return;
    const int start = row_start[v], c = cnt[v];
    const u32* hp = (const u32*)hin;  // row = 64 u32 (2 bf16 each)
    float a0 = 0.f, a1 = 0.f;
    int i = 0;
    for (; i + 4 <= c; i += 4) {
        int2 p0 = edges[start + i], p1 = edges[start + i + 1];
        int2 p2 = edges[start + i + 2], p3 = edges[start + i + 3];
        u32 h0 = hp[(size_t)p0.x * 64 + lane];
        u32 h1 = hp[(size_t)p1.x * 64 + lane];
        u32 h2 = hp[(size_t)p2.x * 64 + lane];
        u32 h3 = hp[(size_t)p3.x * 64 + lane];
        float w0 = __int_as_float(p0.y), w1 = __int_as_float(p1.y);
        float w2 = __int_as_float(p2.y), w3 = __int_as_float(p3.y);
        a0 = fmaf(w0, bf2f((u16)h0), a0); a1 = fmaf(w0, bf2f((u16)(h0 >> 16)), a1);
        a0 = fmaf(w1, bf2f((u16)h1), a0); a1 = fmaf(w1, bf2f((u16)(h1 >> 16)), a1);
        a0 = fmaf(w2, bf2f((u16)h2), a0); a1 = fmaf(w2, bf2f((u16)(h2 >> 16)), a1);
        a0 = fmaf(w3, bf2f((u16)h3), a0); a1 = fmaf(w3, bf2f((u16)(h3 >> 16)), a1);
    }
    for (; i < c; ++i) {
        int2 p = edges[start + i];
        u32 h = hp[(size_t)p.x * 64 + lane];
        float ww = __int_as_float(p.y);
        a0 = fmaf(ww, bf2f((u16)h), a0); a1 = fmaf(ww, bf2f((u16)(h >> 16)), a1);
    }
    float dv = dinv[v], sw = dv * dv;
    u32 hs = hp[(size_t)v * 64 + lane];
    a0 = fmaf(sw, bf2f((u16)hs), a0); a1 = fmaf(sw, bf2f((u16)(hs >> 16)), a1);
    float2 bp = ((const float2*)bias)[lane];
    a0 += bp.x; a1 += bp.y;
    if (RELU) { a0 = fmaxf(a0, 0.f); a1 = fmaxf(a1, 0.f); }
    ((float2*)out)[(size_t)v * 64 + lane] = make_float2(a0, a1);
}

template <bool RELU>
__global__ __launch_bounds__(256) void k_agg64(const u16* __restrict__ hin, const int2* __restrict__ edges,
                                               const int* __restrict__ row_start, const int* __restrict__ cnt,
                                               const float* __restrict__ dinv, const float* __restrict__ bias,
                                               float* __restrict__ out, int N) {
    const int v = blockIdx.x * 4 + (threadIdx.x >> 6);
    const int lane = threadIdx.x & 63;
    if (v >= N) return;
    const int start = row_start[v], c = cnt[v];
    float a0 = 0.f;
    int i = 0;
    for (; i + 4 <= c; i += 4) {
        int2 p0 = edges[start + i], p1 = edges[start + i + 1];
        int2 p2 = edges[start + i + 2], p3 = edges[start + i + 3];
        float h0 = bf2f(hin[(size_t)p0.x * 64 + lane]);
        float h1 = bf2f(hin[(size_t)p1.x * 64 + lane]);
        float h2 = bf2f(hin[(size_t)p2.x * 64 + lane]);
        float h3 = bf2f(hin[(size_t)p3.x * 64 + lane]);
        a0 = fmaf(__int_as_float(p0.y), h0, a0);
        a0 = fmaf(__int_as_float(p1.y), h1, a0);
        a0 = fmaf(__int_as_float(p2.y), h2, a0);
        a0 = fmaf(__int_as_float(p3.y), h3, a0);
    }
    for (; i < c; ++i) {
        int2 p = edges[start + i];
        a0 = fmaf(__int_as_float(p.y), bf2f(hin[(size_t)p.x * 64 + lane]), a0);
    }
    float dv = dinv[v];
    a0 = fmaf(dv * dv, bf2f(hin[(size_t)v * 64 + lane]), a0);
    a0 += bias[lane];
    if (RELU) a0 = fmaxf(a0, 0.f);
    out[(size_t)v * 64 + lane] = a0;
}

// ---------------- launch ----------------

extern "C" void kernel_launch(void* const* d_in, const int* in_sizes, int n_in,
                              void* d_out, int out_size, void* d_ws, size_t ws_size,
                              hipStream_t stream) {
    const float* x = (const float*)d_in[0];
    const int* ei = (const int*)d_in[1];
    const float* eps = (const float*)d_in[2];
    const float* We1 = (const float*)d_in[3];
    const float* be1 = (const float*)d_in[4];
    const float* We2 = (const float*)d_in[5];
    const float* be2 = (const float*)d_in[6];
    const float* Wmu = (const float*)d_in[7];
    const float* bmu = (const float*)d_in[8];
    const float* Wlv = (const float*)d_in[9];
    const float* blv = (const float*)d_in[10];
    const float* Wd1 = (const float*)d_in[11];
    const float* bd1 = (const float*)d_in[12];
    const float* Wd2 = (const float*)d_in[13];
    const float* bd2 = (const float*)d_in[14];

    const int N = in_sizes[0] / 128;  // 50000
    const int E = in_sizes[1] / 2;    // 800000

    // workspace: cnt | fill | cursor(+pad) | dinv | row_start | edges | R1 (bf16 N*128)
    int* cnt = (int*)d_ws;
    int* fill = cnt + N;
    int* cursor = fill + N;
    float* dinv = (float*)(cursor + 64);
    int* row_start = (int*)(dinv + N);
    int2* edges = (int2*)(row_start + N);
    u16* R1 = (u16*)(edges + E);  // bf16 gather buffer, N*128

    // d_out doubles as fp32 ping buffer for agg outputs (fully rewritten at the end)
    float* out_d = (float*)d_out;                 // N*128
    float* out_mu = out_d + (size_t)N * 128;      // N*64
    float* out_lv = out_mu + (size_t)N * 64;      // N*64
    float* H = out_d;                             // fp32 intermediate region
    float* Zbuf = out_d + (size_t)N * 64;         // z lives in out_d[N*64 .. N*128)

    hipMemsetAsync(d_ws, 0, (size_t)(2 * N + 64) * 4, stream);

    k_count<<<dim3((E + 255) / 256), dim3(256), 0, stream>>>(ei, E, cnt);
    k_dinv_alloc<<<dim3((N + 255) / 256), dim3(256), 0, stream>>>(cnt, N, dinv, row_start, cursor);
    k_fill<<<dim3((E + 255) / 256), dim3(256), 0, stream>>>(ei, E, dinv, row_start, fill, edges);

    const int RB2 = (N + 127) / 128;  // RT=2 blocks
    const int RB1 = (N + 63) / 64;    // RT=1 blocks

    // encoder conv1: h1 = x @ W_e1 (bf16), H1 = relu(agg(h1)) fp32
    k_gemm<128, 2, 1, true><<<dim3(2, RB2), dim3(256), 0, stream>>>(x, We1, nullptr, nullptr, nullptr, nullptr, R1, nullptr, nullptr, N, 128);
    k_agg128<true><<<dim3((N + 3) / 4), dim3(256), 0, stream>>>(R1, edges, row_start, cnt, dinv, be1, H, N);
    // encoder conv2: h2 = H1 @ W_e2 (bf16), H2 = agg(h2) fp32 (N x 64)
    k_gemm<128, 1, 1, true><<<dim3(1, RB1), dim3(256), 0, stream>>>(H, We2, nullptr, nullptr, nullptr, nullptr, R1, nullptr, nullptr, N, 64);
    k_agg64<false><<<dim3((N + 3) / 4), dim3(256), 0, stream>>>(R1, edges, row_start, cnt, dinv, be2, H, N);
    // mu / logvar / z fused dual GEMM (reads H2 = out_d[0..N*64), writes z to out_d[N*64..N*128))
    k_gemm<64, 1, 2, false><<<dim3(1, RB1), dim3(256), 0, stream>>>(H, Wmu, Wlv, bmu, blv, eps, out_mu, out_lv, Zbuf, N, 64);
    // decoder conv1: h3 = z @ W_d1 (bf16), H3 = relu(agg(h3)) fp32
    k_gemm<64, 2, 1, true><<<dim3(2, RB2), dim3(256), 0, stream>>>(Zbuf, Wd1, nullptr, nullptr, nullptr, nullptr, R1, nullptr, nullptr, N, 128);
    k_agg128<true><<<dim3((N + 3) / 4), dim3(256), 0, stream>>>(R1, edges, row_start, cnt, dinv, bd1, H, N);
    // decoder conv2: h4 = H3 @ W_d2 (bf16), d = agg(h4) -> out_d
    k_gemm<128, 2, 1, true><<<dim3(2, RB2), dim3(256), 0, stream>>>(H, Wd2, nullptr, nullptr, nullptr, nullptr, R1, nullptr, nullptr, N, 128);
    k_agg128<false><<<dim3((N + 3) / 4), dim3(256), 0, stream>>>(R1, edges, row_start, cnt, dinv, bd2, out_d, N);
}